// Round 14
// baseline (212.065 us; speedup 1.0000x reference)
//
#include <hip/hip_runtime.h>
#include <math.h>

// TemporalSNNClassifier — bit-exact fp32 emulation (absmax 0.0 since r2).
//
// r12 evidence: tloop LDS-return-BW bound — broadcast b128 reads are NOT
// deduped (1024 B/instr); 4.2k cyc/CU/t == 111us. r13/r14-B: class-per-wave
// (8 waves = 8 classes, row = lane): spike reads lane-distinct (all bytes
// useful), W2 wave-uniform (80 floats in SGPRs + 48 via uniform LDS b128).
// Spikes cross as 16-bit packed halves (0x3F80/0): expand = 1 VALU
// (shl16 / and 0xFFFF0000 -> exact 1.0f/+0.0f), 2 VALU/term total.
// r13 failed to compile: hoisted scalar W2 collided with param W2 ->
// renamed to Z0..Z79. Logic unchanged.
//
// FROZEN numerics: k-ascending single-accumulator fmaf chains (GEMM1),
// h-ascending 0..127 fmaf chain over spike 1.0f/0.0f (layer 2; fmaf(s,w,a)
// with s in {0,1} proven bit-exact, acc never -0), bias as one separate
// add, leaky update ((0.9f*mem)+cur)-reset with contraction off,
// spike <=> mem > 1.0f, reset_t == spk_{t-1}.

#define T_STEPS 64
#define IN_DIM  256
#define HID     128
#define NCLS    8

// ---------------- kernel A: cur1 GEMM -> ws ----------------
#define A_THR  256
#define A_ROWS 32
#define A_KQ   16     // float4 k-quads per chunk (64 k)

__global__ __launch_bounds__(A_THR, 2)
void snn_gemm(const float* __restrict__ x, const float* __restrict__ W1,
              const float* __restrict__ b1, float* __restrict__ ws)
{
#pragma clang fp contract(off)
    __shared__ float4 w1c[A_KQ][HID + 2];   // pad: read 2-way max
    __shared__ float4 xc[A_ROWS][A_KQ + 1];

    const int tid  = threadIdx.x;
    const int lane = tid & 63;
    const int wv   = __builtin_amdgcn_readfirstlane(tid >> 6);   // 0..3
    const size_t rowg0 = (size_t)blockIdx.x * A_ROWS;

    float accL[8], accH[8];
    #pragma unroll
    for (int j = 0; j < 8; ++j) { accL[j] = 0.0f; accH[j] = 0.0f; }

    #pragma unroll 1
    for (int ch = 0; ch < 4; ++ch) {
        const int kbase = ch * (A_KQ * 4);
        // stage W1 chunk: 2048 float4, 8 per thread
        #pragma unroll
        for (int s = 0; s < 8; ++s) {
            const int idx = tid + s * A_THR;
            const int h = idx >> 4, kq = idx & 15;
            w1c[kq][h] = *(const float4*)(W1 + (size_t)h * IN_DIM + kbase + kq * 4);
        }
        // stage x chunk: 512 float4, 2 per thread
        #pragma unroll
        for (int s = 0; s < 2; ++s) {
            const int idx = tid + s * A_THR;
            const int rr = idx >> 4, kq = idx & 15;
            xc[rr][kq] = *(const float4*)(x + (rowg0 + rr) * IN_DIM + kbase + kq * 4);
        }
        __syncthreads();

        #pragma unroll 4
        for (int kq = 0; kq < A_KQ; ++kq) {
            const float4 wL = w1c[kq][lane];        // lane-contiguous
            const float4 wH = w1c[kq][64 + lane];
            #pragma unroll
            for (int j = 0; j < 8; ++j) {
                const float4 xv = xc[wv * 8 + j][kq];   // wave-uniform
                float aL = accL[j], aH = accH[j];
                aL = fmaf(xv.x, wL.x, aL);   // k ascending, single acc
                aL = fmaf(xv.y, wL.y, aL);
                aL = fmaf(xv.z, wL.z, aL);
                aL = fmaf(xv.w, wL.w, aL);
                aH = fmaf(xv.x, wH.x, aH);
                aH = fmaf(xv.y, wH.y, aH);
                aH = fmaf(xv.z, wH.z, aH);
                aH = fmaf(xv.w, wH.w, aH);
                accL[j] = aL; accH[j] = aH;
            }
        }
        __syncthreads();
    }

    const float bL = b1[lane], bH = b1[64 + lane];
    #pragma unroll
    for (int j = 0; j < 8; ++j) {
        const size_t rg = rowg0 + wv * 8 + j;
        ws[rg * HID + lane]      = accL[j] + bL;   // one rounded add each
        ws[rg * HID + 64 + lane] = accH[j] + bH;
    }
}

// ---------------- kernel B: temporal loop ----------------
// 256 blocks x 512 thr (8 waves = 8 classes), 1 block/CU.
// Phase a: thread (r=tid>>3, q=tid&7) owns h=16q..16q+15 of row r; packs
// spike pairs ((hi bits)|(lo>>16)) into prow[buf][r][8q..8q+7].
// Phase b: lane = row, class = wave; 32 lane-distinct b64 reads; chain
// expand: lo = u<<16, hi = u & 0xFFFF0000 (exact 1.0f / +0.0f).
#define B_RPB  64
#define B_THR  512
#define PSTR   66     // pair-row stride (u32): 8B-aligned, 2-way-max reads

__global__ __launch_bounds__(B_THR, 1)
void snn_tloop(const float* __restrict__ ws, const float* __restrict__ W2,
               const float* __restrict__ b2, float* __restrict__ out)
{
#pragma clang fp contract(off)
    __shared__ unsigned int prow[2][B_RPB][PSTR];   // 33.8 KB packed spikes
    __shared__ float4 w2t4[NCLS][13];               // W2 tail h=80..127

    const int tid = threadIdx.x;
    const int r   = tid >> 3;            // phase-a row 0..63
    const int q   = tid & 7;             // phase-a h-block
    const int ln  = tid & 63;            // phase-b row
    const int wcls = __builtin_amdgcn_readfirstlane(tid >> 6);   // class

    // stage W2 tail (h = 80..127) for all classes
    if (tid < 128) {
        const int c = tid >> 4, i4 = tid & 15;
        if (i4 < 12)
            w2t4[c][i4] = *(const float4*)(W2 + c * HID + 80 + 4 * i4);
    }

    // W2 head h=0..79: wave-uniform scalars (SGPR-resident)
    const float* __restrict__ w2u = W2 + (size_t)wcls * HID;
#define DW(n) const float Z##n = w2u[n];
    DW(0) DW(1) DW(2) DW(3) DW(4) DW(5) DW(6) DW(7) DW(8) DW(9)
    DW(10) DW(11) DW(12) DW(13) DW(14) DW(15) DW(16) DW(17) DW(18) DW(19)
    DW(20) DW(21) DW(22) DW(23) DW(24) DW(25) DW(26) DW(27) DW(28) DW(29)
    DW(30) DW(31) DW(32) DW(33) DW(34) DW(35) DW(36) DW(37) DW(38) DW(39)
    DW(40) DW(41) DW(42) DW(43) DW(44) DW(45) DW(46) DW(47) DW(48) DW(49)
    DW(50) DW(51) DW(52) DW(53) DW(54) DW(55) DW(56) DW(57) DW(58) DW(59)
    DW(60) DW(61) DW(62) DW(63) DW(64) DW(65) DW(66) DW(67) DW(68) DW(69)
    DW(70) DW(71) DW(72) DW(73) DW(74) DW(75) DW(76) DW(77) DW(78) DW(79)
#undef DW
    const float b2c = b2[wcls];

    // cur1 for this thread's 16 h
    float cur1[16];
    {
        const float* src = ws + ((size_t)blockIdx.x * B_RPB + r) * HID + q * 16;
        #pragma unroll
        for (int i = 0; i < 4; ++i) {
            const float4 v = *(const float4*)(src + 4 * i);
            cur1[4*i+0] = v.x; cur1[4*i+1] = v.y;
            cur1[4*i+2] = v.z; cur1[4*i+3] = v.w;
        }
    }

    float mem1[16], spk1[16];
    #pragma unroll
    for (int i = 0; i < 16; ++i) { mem1[i] = 0.0f; spk1[i] = 0.0f; }
    float m2 = 0.0f, r2 = 0.0f, o = 0.0f;

    #pragma unroll 1
    for (int t = 0; t < T_STEPS; ++t) {
        const int buf = t & 1;
        // phase a: leaky layer-1 (numpy op order, no contraction)
        #pragma unroll
        for (int i = 0; i < 16; ++i) {
            float tmp = 0.9f * mem1[i];   // rounded mul
            tmp = tmp + cur1[i];          // rounded add
            float m = tmp - spk1[i];      // rounded sub
            mem1[i] = m;
            spk1[i] = (m > 1.0f) ? 1.0f : 0.0f;
        }
        // pack pairs: u = bits(spk_odd) | (bits(spk_even) >> 16)
        #pragma unroll
        for (int s = 0; s < 4; ++s) {
            uint2 pv;
            pv.x = __float_as_uint(spk1[4*s+1]) | (__float_as_uint(spk1[4*s+0]) >> 16);
            pv.y = __float_as_uint(spk1[4*s+3]) | (__float_as_uint(spk1[4*s+2]) >> 16);
            *(uint2*)&prow[buf][r][q * 8 + 2 * s] = pv;
        }
        __syncthreads();   // double buffer -> one barrier per timestep

        // phase b: 128-step h-ascending chain; lane-distinct b64 spike reads
        float a = 0.0f;
#define PR2(g, WA, WB, WC, WD) { \
        const uint2 pv = *(const uint2*)&prow[buf][ln][2 * (g)]; \
        a = fmaf(__uint_as_float(pv.x << 16),          WA, a); \
        a = fmaf(__uint_as_float(pv.x & 0xFFFF0000u),  WB, a); \
        a = fmaf(__uint_as_float(pv.y << 16),          WC, a); \
        a = fmaf(__uint_as_float(pv.y & 0xFFFF0000u),  WD, a); }
        PR2(0,  Z0,  Z1,  Z2,  Z3)   PR2(1,  Z4,  Z5,  Z6,  Z7)
        PR2(2,  Z8,  Z9,  Z10, Z11)  PR2(3,  Z12, Z13, Z14, Z15)
        PR2(4,  Z16, Z17, Z18, Z19)  PR2(5,  Z20, Z21, Z22, Z23)
        PR2(6,  Z24, Z25, Z26, Z27)  PR2(7,  Z28, Z29, Z30, Z31)
        PR2(8,  Z32, Z33, Z34, Z35)  PR2(9,  Z36, Z37, Z38, Z39)
        PR2(10, Z40, Z41, Z42, Z43)  PR2(11, Z44, Z45, Z46, Z47)
        PR2(12, Z48, Z49, Z50, Z51)  PR2(13, Z52, Z53, Z54, Z55)
        PR2(14, Z56, Z57, Z58, Z59)  PR2(15, Z60, Z61, Z62, Z63)
        PR2(16, Z64, Z65, Z66, Z67)  PR2(17, Z68, Z69, Z70, Z71)
        PR2(18, Z72, Z73, Z74, Z75)  PR2(19, Z76, Z77, Z78, Z79)
        #pragma unroll
        for (int g = 20; g < 32; ++g) {
            const float4 tw = w2t4[wcls][g - 20];   // wave-uniform b128
            PR2(g, tw.x, tw.y, tw.z, tw.w)
        }
#undef PR2
        // layer-2 leaky update (numpy op order)
        const float c2 = a + b2c;
        float t2 = 0.9f * m2; t2 = t2 + c2; m2 = t2 - r2;
        r2 = (m2 > 1.0f) ? 1.0f : 0.0f;
        o  = o + r2;
    }

    out[((size_t)blockIdx.x * B_RPB + ln) * NCLS + wcls] = o;
}

extern "C" void kernel_launch(void* const* d_in, const int* in_sizes, int n_in,
                              void* d_out, int out_size, void* d_ws, size_t ws_size,
                              hipStream_t stream) {
    const float* x  = (const float*)d_in[0];
    const float* W1 = (const float*)d_in[1];
    const float* b1 = (const float*)d_in[2];
    const float* W2 = (const float*)d_in[3];
    const float* b2 = (const float*)d_in[4];
    float* out = (float*)d_out;
    float* cur_ws = (float*)d_ws;        // [BATCH x HID] = 8 MB

    const int batch = in_sizes[0] / IN_DIM;          // 16384
    snn_gemm<<<batch / A_ROWS, A_THR, 0, stream>>>(x, W1, b1, cur_ws);
    snn_tloop<<<batch / B_RPB, B_THR, 0, stream>>>(cur_ws, W2, b2, out);
}

// Round 15
// 163.726 us; speedup vs baseline: 1.2952x; 1.2952x over previous
//
#include <hip/hip_runtime.h>
#include <math.h>

// TemporalSNNClassifier — bit-exact fp32 emulation (absmax 0.0 since r2).
//
// r14 evidence: SGPR=112 maxed -> 80 hoisted W2 scalars exceed the ~102
// budget; W2 re-s_loaded EVERY timestep, lgkm serialized into the chain
// (VALU 53%, 131us). Hard facts: W2 fits in no register file; broadcast
// LDS reads waste 8x; per-t W2 re-reads are the tax.
// r15: batch 4 timesteps per chain pass. Layer-2 is off the critical path
// (mem1(t+1) needs only mem1/spk1), so phase-a runs 4 steps ahead into LDS
// (pair-packed spikes), then one W2 pass (uniform LDS b128) feeds 4
// independent h-ascending chains. W2 traffic /4, no SGPR pressure,
// 2 barriers per 4 t. pk row-stride 260 u32 (=4 mod 32) -> 8 accesses/bank
// on write and read = conflict-free at throughput.
// gemm: UNCHANGED from r13 (one subsystem per round) — at tloop~50us it
// tops the dispatch table next round and exposes its counters.
//
// FROZEN numerics: k-ascending single-accumulator fmaf chains (GEMM1),
// h-ascending 0..127 fmaf chain per (row,class,t) over spike 1.0f/+0.0f
// (fmaf(s,w,a), s in {0,1}, acc never -0: bit-exact), bias as one separate
// add, leaky update ((0.9f*mem)+cur)-reset with contraction off,
// spike <=> mem > 1.0f, reset_t == spk_{t-1}.

#define T_STEPS 64
#define IN_DIM  256
#define HID     128
#define NCLS    8

// ---------------- kernel A: cur1 GEMM -> ws (r13 verbatim) ----------------
#define A_THR  256
#define A_ROWS 32
#define A_KQ   16     // float4 k-quads per chunk (64 k)

__global__ __launch_bounds__(A_THR, 2)
void snn_gemm(const float* __restrict__ x, const float* __restrict__ W1,
              const float* __restrict__ b1, float* __restrict__ ws)
{
#pragma clang fp contract(off)
    __shared__ float4 w1c[A_KQ][HID + 2];
    __shared__ float4 xc[A_ROWS][A_KQ + 1];

    const int tid  = threadIdx.x;
    const int lane = tid & 63;
    const int wv   = __builtin_amdgcn_readfirstlane(tid >> 6);   // 0..3
    const size_t rowg0 = (size_t)blockIdx.x * A_ROWS;

    float accL[8], accH[8];
    #pragma unroll
    for (int j = 0; j < 8; ++j) { accL[j] = 0.0f; accH[j] = 0.0f; }

    #pragma unroll 1
    for (int ch = 0; ch < 4; ++ch) {
        const int kbase = ch * (A_KQ * 4);
        #pragma unroll
        for (int s = 0; s < 8; ++s) {
            const int idx = tid + s * A_THR;
            const int h = idx >> 4, kq = idx & 15;
            w1c[kq][h] = *(const float4*)(W1 + (size_t)h * IN_DIM + kbase + kq * 4);
        }
        #pragma unroll
        for (int s = 0; s < 2; ++s) {
            const int idx = tid + s * A_THR;
            const int rr = idx >> 4, kq = idx & 15;
            xc[rr][kq] = *(const float4*)(x + (rowg0 + rr) * IN_DIM + kbase + kq * 4);
        }
        __syncthreads();

        #pragma unroll 4
        for (int kq = 0; kq < A_KQ; ++kq) {
            const float4 wL = w1c[kq][lane];
            const float4 wH = w1c[kq][64 + lane];
            #pragma unroll
            for (int j = 0; j < 8; ++j) {
                const float4 xv = xc[wv * 8 + j][kq];
                float aL = accL[j], aH = accH[j];
                aL = fmaf(xv.x, wL.x, aL);   // k ascending, single acc
                aL = fmaf(xv.y, wL.y, aL);
                aL = fmaf(xv.z, wL.z, aL);
                aL = fmaf(xv.w, wL.w, aL);
                aH = fmaf(xv.x, wH.x, aH);
                aH = fmaf(xv.y, wH.y, aH);
                aH = fmaf(xv.z, wH.z, aH);
                aH = fmaf(xv.w, wH.w, aH);
                accL[j] = aL; accH[j] = aH;
            }
        }
        __syncthreads();
    }

    const float bL = b1[lane], bH = b1[64 + lane];
    #pragma unroll
    for (int j = 0; j < 8; ++j) {
        const size_t rg = rowg0 + wv * 8 + j;
        ws[rg * HID + lane]      = accL[j] + bL;
        ws[rg * HID + 64 + lane] = accH[j] + bH;
    }
}

// ---------------- kernel B: temporal loop, 4-t batched ----------------
// 512 blocks x 256 thr (4 waves), 2 blocks/CU.
// phase a: thread (r=tid>>3, q=tid&7) owns h=16q..15; packs spike pairs
//   (hi16 odd | lo16 even>>16) -> pk[r][j][8q..8q+7], j = t&3.
// chain: lane -> row=lane&31, cls=2*wave+(lane>>5); per gg (8 h):
//   2 uniform W2 float4 + 4 uint4 spike reads (j=0..3) + 32 expand+32 fmaf.
#define B_RPB  32
#define B_THR  256
#define RSTR   260    // pk row stride (u32); 260 mod 32 = 4 -> staggered banks

__global__ __launch_bounds__(B_THR, 2)
void snn_tloop(const float* __restrict__ ws, const float* __restrict__ W2,
               const float* __restrict__ b2, float* __restrict__ out)
{
#pragma clang fp contract(off)
    __shared__ unsigned int pk[B_RPB * RSTR];   // 33.3 KB packed spikes
    __shared__ float4 w2l[NCLS * 32];           // 4 KB: [cls][g]

    const int tid = threadIdx.x;
    const int r   = tid >> 3;            // phase-a row 0..31
    const int q   = tid & 7;             // phase-a h-block

    // stage W2: 256 float4, one per thread ([cls= tid>>5][g= tid&31])
    w2l[tid] = ((const float4*)W2)[tid];

    // cur1 for this thread's 16 h
    float cur1[16];
    {
        const float* src = ws + ((size_t)blockIdx.x * B_RPB + r) * HID + q * 16;
        #pragma unroll
        for (int i = 0; i < 4; ++i) {
            const float4 v = *(const float4*)(src + 4 * i);
            cur1[4*i+0] = v.x; cur1[4*i+1] = v.y;
            cur1[4*i+2] = v.z; cur1[4*i+3] = v.w;
        }
    }

    // chain identity
    const int lane = tid & 63;
    const int brow = lane & 31;
    const int bcls = 2 * (tid >> 6) + (lane >> 5);
    const float b2c = b2[bcls];
    const float4* __restrict__ w2p = &w2l[bcls * 32];

    float mem1[16], spk1[16];
    #pragma unroll
    for (int i = 0; i < 16; ++i) { mem1[i] = 0.0f; spk1[i] = 0.0f; }
    float m2 = 0.0f, r2v = 0.0f, o = 0.0f;

    #pragma unroll 1
    for (int ts = 0; ts < T_STEPS; ts += 4) {
        // ---- 4x phase a (layer-1 leaky, numpy op order, no contraction) ----
        #pragma unroll
        for (int j = 0; j < 4; ++j) {
            #pragma unroll
            for (int i = 0; i < 16; ++i) {
                float tmp = 0.9f * mem1[i];   // rounded mul
                tmp = tmp + cur1[i];          // rounded add
                float m = tmp - spk1[i];      // rounded sub
                mem1[i] = m;
                spk1[i] = (m > 1.0f) ? 1.0f : 0.0f;
            }
            unsigned int* dst = &pk[r * RSTR + j * 64 + q * 8];
            #pragma unroll
            for (int s = 0; s < 2; ++s) {
                uint4 pv;
                pv.x = __float_as_uint(spk1[8*s+1]) | (__float_as_uint(spk1[8*s+0]) >> 16);
                pv.y = __float_as_uint(spk1[8*s+3]) | (__float_as_uint(spk1[8*s+2]) >> 16);
                pv.z = __float_as_uint(spk1[8*s+5]) | (__float_as_uint(spk1[8*s+4]) >> 16);
                pv.w = __float_as_uint(spk1[8*s+7]) | (__float_as_uint(spk1[8*s+6]) >> 16);
                *(uint4*)(dst + 4 * s) = pv;
            }
        }
        __syncthreads();   // spikes for 4 t visible

        // ---- chain pass: one W2 sweep feeds 4 independent chains ----
        float a0 = 0.0f, a1 = 0.0f, a2 = 0.0f, a3 = 0.0f;
        const unsigned int* src = &pk[brow * RSTR];
#define LO(u) __uint_as_float((u) << 16)            /* even h: 1.0f / +0.0f */
#define HI(u) __uint_as_float((u) & 0xFFFF0000u)    /* odd  h: 1.0f / +0.0f */
#define TR(A, P) \
        A = fmaf(LO(P.x), wA.x, A); A = fmaf(HI(P.x), wA.y, A); \
        A = fmaf(LO(P.y), wA.z, A); A = fmaf(HI(P.y), wA.w, A); \
        A = fmaf(LO(P.z), wB.x, A); A = fmaf(HI(P.z), wB.y, A); \
        A = fmaf(LO(P.w), wB.z, A); A = fmaf(HI(P.w), wB.w, A);
        #pragma unroll
        for (int gg = 0; gg < 16; ++gg) {
            const float4 wA = w2p[2 * gg];         // W2[cls][8gg..8gg+3]
            const float4 wB = w2p[2 * gg + 1];     // W2[cls][8gg+4..8gg+7]
            const uint4 p0 = *(const uint4*)(src + 0 * 64 + 4 * gg);
            const uint4 p1 = *(const uint4*)(src + 1 * 64 + 4 * gg);
            const uint4 p2 = *(const uint4*)(src + 2 * 64 + 4 * gg);
            const uint4 p3 = *(const uint4*)(src + 3 * 64 + 4 * gg);
            TR(a0, p0) TR(a1, p1) TR(a2, p2) TR(a3, p3)
        }
#undef TR
#undef LO
#undef HI
        __syncthreads();   // pk consumed; next superstep may overwrite

        // ---- layer-2 leaky updates, j ascending (numpy op order) ----
        const float aa[4] = {a0, a1, a2, a3};
        #pragma unroll
        for (int j = 0; j < 4; ++j) {
            const float c2 = aa[j] + b2c;
            float t2 = 0.9f * m2; t2 = t2 + c2; m2 = t2 - r2v;
            r2v = (m2 > 1.0f) ? 1.0f : 0.0f;
            o = o + r2v;
        }
    }

    out[((size_t)blockIdx.x * B_RPB + brow) * NCLS + bcls] = o;
}

extern "C" void kernel_launch(void* const* d_in, const int* in_sizes, int n_in,
                              void* d_out, int out_size, void* d_ws, size_t ws_size,
                              hipStream_t stream) {
    const float* x  = (const float*)d_in[0];
    const float* W1 = (const float*)d_in[1];
    const float* b1 = (const float*)d_in[2];
    const float* W2 = (const float*)d_in[3];
    const float* b2 = (const float*)d_in[4];
    float* out = (float*)d_out;
    float* cur_ws = (float*)d_ws;        // [BATCH x HID] = 8 MB

    const int batch = in_sizes[0] / IN_DIM;          // 16384
    snn_gemm<<<batch / A_ROWS, A_THR, 0, stream>>>(x, W1, b1, cur_ws);
    snn_tloop<<<batch / B_RPB, B_THR, 0, stream>>>(cur_ws, W2, b2, out);
}

// Round 16
// 162.512 us; speedup vs baseline: 1.3049x; 1.0075x over previous
//
#include <hip/hip_runtime.h>
#include <math.h>

// TemporalSNNClassifier — bit-exact fp32 emulation (absmax 0.0 since r2).
//
// r15 evidence: tloop 83us @ VALU 84.8% (done for now); gemm invariant at
// ~81us across 4 implementations. Unified law (r10+r12+m136): 16B-per-lane
// reads are NEVER deduplicated — a wave-uniform b128 (global OR LDS) moves
// 64x16B and serializes on the bank quad (~64cyc). gemm's 8 uniform x-quad
// reads per kq == the 81us floor. Fix: x as 4x ds_read_b32 broadcasts
// (m136: b32 same-address broadcast is FREE), stored c-major stride-33 so
// the 4 reads are 132B apart (compiler cannot re-merge into b128).
// W1 reads stay lane-contiguous b128 (all bytes useful). tloop unchanged.
//
// FROZEN numerics: k-ascending single-accumulator fmaf chains (GEMM1),
// h-ascending 0..127 fmaf chain per (row,class,t) over spike 1.0f/+0.0f
// (fmaf(s,w,a), s in {0,1}, acc never -0: bit-exact), bias as one separate
// add, leaky update ((0.9f*mem)+cur)-reset with contraction off,
// spike <=> mem > 1.0f, reset_t == spk_{t-1}.

#define T_STEPS 64
#define IN_DIM  256
#define HID     128
#define NCLS    8

// ---------------- kernel A: cur1 GEMM -> ws ----------------
#define A_THR  256
#define A_ROWS 32
#define A_KQ   16     // float4 k-quads per chunk (64 k)

__global__ __launch_bounds__(A_THR, 2)
void snn_gemm(const float* __restrict__ x, const float* __restrict__ W1,
              const float* __restrict__ b1, float* __restrict__ ws)
{
#pragma clang fp contract(off)
    __shared__ float4 w1c[A_KQ][HID + 2];   // 33.3 KB, lane-contig reads
    __shared__ float  xcf[64 * 33];         // 8.4 KB, c-major stride 33

    const int tid  = threadIdx.x;
    const int lane = tid & 63;
    const int wv   = __builtin_amdgcn_readfirstlane(tid >> 6);   // 0..3
    const size_t rowg0 = (size_t)blockIdx.x * A_ROWS;

    float accL[8], accH[8];
    #pragma unroll
    for (int j = 0; j < 8; ++j) { accL[j] = 0.0f; accH[j] = 0.0f; }

    #pragma unroll 1
    for (int ch = 0; ch < 4; ++ch) {
        const int kbase = ch * (A_KQ * 4);
        // stage W1 chunk: 2048 float4, 8 per thread (coalesced per h-row)
        #pragma unroll
        for (int s = 0; s < 8; ++s) {
            const int idx = tid + s * A_THR;
            const int h = idx >> 4, kq = idx & 15;
            w1c[kq][h] = *(const float4*)(W1 + (size_t)h * IN_DIM + kbase + kq * 4);
        }
        // stage x chunk c-major: quad (rr,kq) -> xcf[(4kq+c)*33 + rr]
        // write banks (4kq+c+rr) mod 32 -> 2-way max (free)
        #pragma unroll
        for (int s = 0; s < 2; ++s) {
            const int idx = tid + s * A_THR;
            const int rr = idx >> 4, kq = idx & 15;
            const float4 v = *(const float4*)(x + (rowg0 + rr) * IN_DIM + kbase + kq * 4);
            xcf[(4 * kq + 0) * 33 + rr] = v.x;
            xcf[(4 * kq + 1) * 33 + rr] = v.y;
            xcf[(4 * kq + 2) * 33 + rr] = v.z;
            xcf[(4 * kq + 3) * 33 + rr] = v.w;
        }
        __syncthreads();

        #pragma unroll 4
        for (int kq = 0; kq < A_KQ; ++kq) {
            const float4 wL = w1c[kq][lane];        // lane-contig 1KB, 8cyc
            const float4 wH = w1c[kq][64 + lane];
            #pragma unroll
            for (int j = 0; j < 8; ++j) {
                const int rb = wv * 8 + j;
                // 4 separate b32 broadcasts (132B apart -> no b128 merge)
                const float x0 = xcf[(4 * kq + 0) * 33 + rb];
                const float x1 = xcf[(4 * kq + 1) * 33 + rb];
                const float x2 = xcf[(4 * kq + 2) * 33 + rb];
                const float x3 = xcf[(4 * kq + 3) * 33 + rb];
                float aL = accL[j], aH = accH[j];
                aL = fmaf(x0, wL.x, aL);   // k ascending, single acc
                aL = fmaf(x1, wL.y, aL);
                aL = fmaf(x2, wL.z, aL);
                aL = fmaf(x3, wL.w, aL);
                aH = fmaf(x0, wH.x, aH);
                aH = fmaf(x1, wH.y, aH);
                aH = fmaf(x2, wH.z, aH);
                aH = fmaf(x3, wH.w, aH);
                accL[j] = aL; accH[j] = aH;
            }
        }
        __syncthreads();
    }

    const float bL = b1[lane], bH = b1[64 + lane];
    #pragma unroll
    for (int j = 0; j < 8; ++j) {
        const size_t rg = rowg0 + wv * 8 + j;
        ws[rg * HID + lane]      = accL[j] + bL;   // one rounded add each
        ws[rg * HID + 64 + lane] = accH[j] + bH;
    }
}

// ---------------- kernel B: temporal loop, 4-t batched (r15 verbatim) -----
#define B_RPB  32
#define B_THR  256
#define RSTR   260    // pk row stride (u32); =4 mod 32 -> staggered banks

__global__ __launch_bounds__(B_THR, 2)
void snn_tloop(const float* __restrict__ ws, const float* __restrict__ W2,
               const float* __restrict__ b2, float* __restrict__ out)
{
#pragma clang fp contract(off)
    __shared__ unsigned int pk[B_RPB * RSTR];   // 33.3 KB packed spikes
    __shared__ float4 w2l[NCLS * 32];           // 4 KB: [cls][g]

    const int tid = threadIdx.x;
    const int r   = tid >> 3;            // phase-a row 0..31
    const int q   = tid & 7;             // phase-a h-block

    w2l[tid] = ((const float4*)W2)[tid];

    float cur1[16];
    {
        const float* src = ws + ((size_t)blockIdx.x * B_RPB + r) * HID + q * 16;
        #pragma unroll
        for (int i = 0; i < 4; ++i) {
            const float4 v = *(const float4*)(src + 4 * i);
            cur1[4*i+0] = v.x; cur1[4*i+1] = v.y;
            cur1[4*i+2] = v.z; cur1[4*i+3] = v.w;
        }
    }

    const int lane = tid & 63;
    const int brow = lane & 31;
    const int bcls = 2 * (tid >> 6) + (lane >> 5);
    const float b2c = b2[bcls];
    const float4* __restrict__ w2p = &w2l[bcls * 32];

    float mem1[16], spk1[16];
    #pragma unroll
    for (int i = 0; i < 16; ++i) { mem1[i] = 0.0f; spk1[i] = 0.0f; }
    float m2 = 0.0f, r2v = 0.0f, o = 0.0f;

    #pragma unroll 1
    for (int ts = 0; ts < T_STEPS; ts += 4) {
        #pragma unroll
        for (int j = 0; j < 4; ++j) {
            #pragma unroll
            for (int i = 0; i < 16; ++i) {
                float tmp = 0.9f * mem1[i];   // rounded mul
                tmp = tmp + cur1[i];          // rounded add
                float m = tmp - spk1[i];      // rounded sub
                mem1[i] = m;
                spk1[i] = (m > 1.0f) ? 1.0f : 0.0f;
            }
            unsigned int* dst = &pk[r * RSTR + j * 64 + q * 8];
            #pragma unroll
            for (int s = 0; s < 2; ++s) {
                uint4 pv;
                pv.x = __float_as_uint(spk1[8*s+1]) | (__float_as_uint(spk1[8*s+0]) >> 16);
                pv.y = __float_as_uint(spk1[8*s+3]) | (__float_as_uint(spk1[8*s+2]) >> 16);
                pv.z = __float_as_uint(spk1[8*s+5]) | (__float_as_uint(spk1[8*s+4]) >> 16);
                pv.w = __float_as_uint(spk1[8*s+7]) | (__float_as_uint(spk1[8*s+6]) >> 16);
                *(uint4*)(dst + 4 * s) = pv;
            }
        }
        __syncthreads();

        float a0 = 0.0f, a1 = 0.0f, a2 = 0.0f, a3 = 0.0f;
        const unsigned int* src = &pk[brow * RSTR];
#define LO(u) __uint_as_float((u) << 16)
#define HI(u) __uint_as_float((u) & 0xFFFF0000u)
#define TR(A, P) \
        A = fmaf(LO(P.x), wA.x, A); A = fmaf(HI(P.x), wA.y, A); \
        A = fmaf(LO(P.y), wA.z, A); A = fmaf(HI(P.y), wA.w, A); \
        A = fmaf(LO(P.z), wB.x, A); A = fmaf(HI(P.z), wB.y, A); \
        A = fmaf(LO(P.w), wB.z, A); A = fmaf(HI(P.w), wB.w, A);
        #pragma unroll
        for (int gg = 0; gg < 16; ++gg) {
            const float4 wA = w2p[2 * gg];
            const float4 wB = w2p[2 * gg + 1];
            const uint4 p0 = *(const uint4*)(src + 0 * 64 + 4 * gg);
            const uint4 p1 = *(const uint4*)(src + 1 * 64 + 4 * gg);
            const uint4 p2 = *(const uint4*)(src + 2 * 64 + 4 * gg);
            const uint4 p3 = *(const uint4*)(src + 3 * 64 + 4 * gg);
            TR(a0, p0) TR(a1, p1) TR(a2, p2) TR(a3, p3)
        }
#undef TR
#undef LO
#undef HI
        __syncthreads();

        const float aa[4] = {a0, a1, a2, a3};
        #pragma unroll
        for (int j = 0; j < 4; ++j) {
            const float c2 = aa[j] + b2c;
            float t2 = 0.9f * m2; t2 = t2 + c2; m2 = t2 - r2v;
            r2v = (m2 > 1.0f) ? 1.0f : 0.0f;
            o = o + r2v;
        }
    }

    out[((size_t)blockIdx.x * B_RPB + brow) * NCLS + bcls] = o;
}

extern "C" void kernel_launch(void* const* d_in, const int* in_sizes, int n_in,
                              void* d_out, int out_size, void* d_ws, size_t ws_size,
                              hipStream_t stream) {
    const float* x  = (const float*)d_in[0];
    const float* W1 = (const float*)d_in[1];
    const float* b1 = (const float*)d_in[2];
    const float* W2 = (const float*)d_in[3];
    const float* b2 = (const float*)d_in[4];
    float* out = (float*)d_out;
    float* cur_ws = (float*)d_ws;        // [BATCH x HID] = 8 MB

    const int batch = in_sizes[0] / IN_DIM;          // 16384
    snn_gemm<<<batch / A_ROWS, A_THR, 0, stream>>>(x, W1, b1, cur_ws);
    snn_tloop<<<batch / B_RPB, B_THR, 0, stream>>>(cur_ws, W2, b2, out);
}